// Round 3
// baseline (385.496 us; speedup 1.0000x reference)
//
#include <hip/hip_runtime.h>
#include <hip/hip_bf16.h>

// Problem constants (reference: N=2048, D=512, T=0.1, sigma=1, 4 classes)
#define D 512
#define BM 16          // rows per block in main kernel
#define THREADS 512    // threads per block in main kernel (8 waves)
#define BCOLS 1024     // columns per chunk (2 per thread)
#define INV_T 10.0f
#define INF_VAL 1e8f

__device__ inline float wave_reduce_sum(float v) {
#pragma unroll
  for (int off = 32; off > 0; off >>= 1) v += __shfl_xor(v, off);
  return v;
}

__device__ inline float wave_reduce_max(float v) {
#pragma unroll
  for (int off = 32; off > 0; off >>= 1) v = fmaxf(v, __shfl_xor(v, off));
  return v;
}

// invn[row] = 1 / max(||z_row||, 1e-12), row in [0, 2N)
__global__ __launch_bounds__(256) void k_rownorm(const float* __restrict__ zi,
                                                 const float* __restrict__ zj,
                                                 float* __restrict__ invn, int N) {
  __shared__ float scratch[4];
  int row = blockIdx.x;
  const float* src = (row < N) ? (zi + (size_t)row * D) : (zj + (size_t)(row - N) * D);
  float ss = 0.f;
  for (int k = threadIdx.x; k < D; k += 256) {
    float v = src[k];
    ss = fmaf(v, v, ss);
  }
  ss = wave_reduce_sum(ss);
  int lane = threadIdx.x & 63, wv = threadIdx.x >> 6;
  if (lane == 0) scratch[wv] = ss;
  __syncthreads();
  if (threadIdx.x == 0) {
    float t = scratch[0] + scratch[1] + scratch[2] + scratch[3];
    invn[row] = 1.0f / fmaxf(sqrtf(t), 1e-12f);
  }
}

// shalf[j] = sum_i same(i,j)*exp(-0.5*(p_i-p_j)^2)  (includes i==j term == 1)
// sinv[j] = 1 / (2*shalf[j] - 1)  == 1 / column-sum S[b] for b%N == j
__global__ __launch_bounds__(256) void k_colsum(const int* __restrict__ labels,
                                                const float* __restrict__ zpos,
                                                float* __restrict__ sinv, int N) {
  __shared__ float scratch[4];
  int j = blockIdx.x;
  int lj = labels[j];
  float pj = zpos[j];
  float s = 0.f;
  for (int i = threadIdx.x; i < N; i += 256) {
    if (labels[i] == lj) {
      float d = zpos[i] - pj;
      s += __expf(-0.5f * d * d);
    }
  }
  s = wave_reduce_sum(s);
  int lane = threadIdx.x & 63, wv = threadIdx.x >> 6;
  if (lane == 0) scratch[wv] = s;
  __syncthreads();
  if (threadIdx.x == 0) {
    float t = scratch[0] + scratch[1] + scratch[2] + scratch[3];
    sinv[j] = 1.0f / (2.0f * t - 1.0f);
  }
}

// tt[i] = sum_j same(i,j)*rbf(i,j)*sinv[j]; wsum[a] = 2*tt[a%N] - sinv[a%N]
__global__ __launch_bounds__(256) void k_tt(const int* __restrict__ labels,
                                            const float* __restrict__ zpos,
                                            const float* __restrict__ sinv,
                                            float* __restrict__ tt, int N) {
  __shared__ float scratch[4];
  int i = blockIdx.x;
  int li = labels[i];
  float pi = zpos[i];
  float s = 0.f;
  for (int j = threadIdx.x; j < N; j += 256) {
    if (labels[j] == li) {
      float d = zpos[j] - pi;
      s += __expf(-0.5f * d * d) * sinv[j];
    }
  }
  s = wave_reduce_sum(s);
  int lane = threadIdx.x & 63, wv = threadIdx.x >> 6;
  if (lane == 0) scratch[wv] = s;
  __syncthreads();
  if (threadIdx.x == 0) {
    tt[i] = scratch[0] + scratch[1] + scratch[2] + scratch[3];
  }
}

// Main fused kernel: per 16-row block, stream all 2N columns, compute sims,
// online logsumexp per row + cross = sum_b fw[a,b]*sim[a,b].
// partial[a] = cross_a - wsum_a * lse_a
__global__ __launch_bounds__(THREADS) void k_main(
    const float* __restrict__ zi, const float* __restrict__ zj,
    const int* __restrict__ labels, const float* __restrict__ zpos,
    const float* __restrict__ invn, const float* __restrict__ sinv,
    const float* __restrict__ tt, float* __restrict__ partial, int N) {
  __shared__ float4 za4[BM][D / 4];       // 32 KB: row tile, pre-scaled by invn
  __shared__ float simbuf[BM][BCOLS];     // 64 KB: sims for current column chunk

  const int twoN = 2 * N;
  const int tid = threadIdx.x;
  const int lane = tid & 63;
  const int wave = tid >> 6;              // 8 waves, 2 rows each
  const int rowBase = blockIdx.x * BM;

  // stage & normalize the 16 A-rows into LDS
  for (int idx = tid; idx < BM * (D / 4); idx += THREADS) {
    int r = idx >> 7;                     // / (D/4 == 128)
    int k4 = idx & (D / 4 - 1);
    int grow = rowBase + r;
    const float* src = (grow < N) ? (zi + (size_t)grow * D) : (zj + (size_t)(grow - N) * D);
    float4 v = reinterpret_cast<const float4*>(src)[k4];
    float sc = invn[grow];
    v.x *= sc; v.y *= sc; v.z *= sc; v.w *= sc;
    za4[r][k4] = v;
  }

  // per-wave row metadata + running online-softmax state (replicated per lane)
  float run_m[2] = {-1e30f, -1e30f};
  float run_s[2] = {0.f, 0.f};
  float run_c[2] = {0.f, 0.f};
  int rlab[2];
  float rpos[2];
#pragma unroll
  for (int rr = 0; rr < 2; ++rr) {
    int grow = rowBase + wave * 2 + rr;
    int ir = (grow >= N) ? grow - N : grow;
    rlab[rr] = labels[ir];
    rpos[rr] = zpos[ir];
  }
  __syncthreads();

  for (int base = 0; base < twoN; base += BCOLS) {
    // ---- compute phase: 2 columns per thread, fp32 dot over D ----
    int b0 = base + tid;
    int b1 = base + THREADS + tid;
    const float4* zb0 = reinterpret_cast<const float4*>(
        (b0 < N) ? (zi + (size_t)b0 * D) : (zj + (size_t)(b0 - N) * D));
    const float4* zb1 = reinterpret_cast<const float4*>(
        (b1 < N) ? (zi + (size_t)b1 * D) : (zj + (size_t)(b1 - N) * D));
    float acc0[BM], acc1[BM];
#pragma unroll
    for (int r = 0; r < BM; ++r) { acc0[r] = 0.f; acc1[r] = 0.f; }
#pragma unroll 2
    for (int k4 = 0; k4 < D / 4; ++k4) {
      float4 v0 = zb0[k4];
      float4 v1 = zb1[k4];
#pragma unroll
      for (int r = 0; r < BM; ++r) {
        float4 a = za4[r][k4];   // wave-uniform address -> LDS broadcast
        acc0[r] = fmaf(a.w, v0.w, fmaf(a.z, v0.z, fmaf(a.y, v0.y, fmaf(a.x, v0.x, acc0[r]))));
        acc1[r] = fmaf(a.w, v1.w, fmaf(a.z, v1.z, fmaf(a.y, v1.y, fmaf(a.x, v1.x, acc1[r]))));
      }
    }
    float in0 = invn[b0] * INV_T;
    float in1 = invn[b1] * INV_T;
#pragma unroll
    for (int r = 0; r < BM; ++r) {
      float s0 = acc0[r] * in0;
      float s1 = acc1[r] * in1;
      if (rowBase + r == b0) s0 -= INF_VAL;   // -INF on the true diagonal only
      if (rowBase + r == b1) s1 -= INF_VAL;
      simbuf[r][tid] = s0;
      simbuf[r][tid + THREADS] = s1;
    }
    __syncthreads();

    // ---- reduction phase: wave w owns rows 2w, 2w+1 ----
#pragma unroll
    for (int rr = 0; rr < 2; ++rr) {
      int r = wave * 2 + rr;
      int grow = rowBase + r;
      float lmax = -1e30f;
      float cl = 0.f;
#pragma unroll
      for (int j = 0; j < BCOLS / 64; ++j) {
        int idx = j * 64 + lane;
        float sv = simbuf[r][idx];
        lmax = fmaxf(lmax, sv);
        int b = base + idx;
        if (b != grow) {                       // mask excludes exact diagonal
          int jb = (b >= N) ? b - N : b;
          if (labels[jb] == rlab[rr]) {        // label-agreement mask
            float d = zpos[jb] - rpos[rr];
            float fw = __expf(-0.5f * d * d) * sinv[jb];
            cl = fmaf(fw, sv, cl);
          }
        }
      }
      lmax = wave_reduce_max(lmax);
      float lsum = 0.f;
#pragma unroll
      for (int j = 0; j < BCOLS / 64; ++j) {
        lsum += __expf(simbuf[r][j * 64 + lane] - lmax);
      }
      lsum = wave_reduce_sum(lsum);
      cl = wave_reduce_sum(cl);
      // merge chunk (lmax, lsum) into running (m, s)
      float nm = fmaxf(run_m[rr], lmax);
      run_s[rr] = run_s[rr] * __expf(run_m[rr] - nm) + lsum * __expf(lmax - nm);
      run_m[rr] = nm;
      run_c[rr] += cl;
    }
    __syncthreads();   // simbuf free for next chunk
  }

#pragma unroll
  for (int rr = 0; rr < 2; ++rr) {
    if (lane == 0) {
      int grow = rowBase + wave * 2 + rr;
      int ir = (grow >= N) ? grow - N : grow;
      float lse = run_m[rr] + __logf(run_s[rr]);
      float wsum = 2.f * tt[ir] - sinv[ir];
      partial[grow] = run_c[rr] - wsum * lse;
    }
  }
}

// loss = (-1/N) * sum_a partial[a]   (deterministic single-block reduction)
__global__ __launch_bounds__(256) void k_final(const float* __restrict__ partial,
                                               float* __restrict__ out, int N) {
  __shared__ float scratch[4];
  float s = 0.f;
  for (int a = threadIdx.x; a < 2 * N; a += 256) s += partial[a];
  s = wave_reduce_sum(s);
  int lane = threadIdx.x & 63, wv = threadIdx.x >> 6;
  if (lane == 0) scratch[wv] = s;
  __syncthreads();
  if (threadIdx.x == 0) {
    float t = scratch[0] + scratch[1] + scratch[2] + scratch[3];
    out[0] = (-1.0f / (float)N) * t;
  }
}

extern "C" void kernel_launch(void* const* d_in, const int* in_sizes, int n_in,
                              void* d_out, int out_size, void* d_ws, size_t ws_size,
                              hipStream_t stream) {
  (void)n_in; (void)out_size; (void)ws_size;
  const float* zi = (const float*)d_in[0];
  const float* zj = (const float*)d_in[1];
  const int* labels = (const int*)d_in[2];
  const float* zpos = (const float*)d_in[3];
  float* out = (float*)d_out;

  const int N = in_sizes[2];       // 2048 (labels count)
  const int twoN = 2 * N;

  // workspace layout (floats): invn[2N] | sinv[N] | tt[N] | partial[2N]
  float* ws = (float*)d_ws;
  float* invn = ws;
  float* sinv = invn + twoN;
  float* tt = sinv + N;
  float* partial = tt + N;

  k_rownorm<<<twoN, 256, 0, stream>>>(zi, zj, invn, N);
  k_colsum<<<N, 256, 0, stream>>>(labels, zpos, sinv, N);
  k_tt<<<N, 256, 0, stream>>>(labels, zpos, sinv, tt, N);
  k_main<<<twoN / BM, THREADS, 0, stream>>>(zi, zj, labels, zpos, invn, sinv, tt, partial, N);
  k_final<<<1, 256, 0, stream>>>(partial, out, N);
}

// Round 4
// 86.452 us; speedup vs baseline: 4.4591x; 4.4591x over previous
//
#include <hip/hip_runtime.h>
#include <hip/hip_bf16.h>

// Problem constants (reference: N=2048, D=512, T=0.1, sigma=1, 4 classes)
#define D 512
#define INV_T 10.0f
#define INF_VAL 1e8f
#define NCT 32          // column tiles in k_mfma (4096 / 128)

typedef short bf16x8 __attribute__((ext_vector_type(8)));
typedef float f32x4 __attribute__((ext_vector_type(4)));

__device__ inline float wave_reduce_sum(float v) {
#pragma unroll
  for (int off = 32; off > 0; off >>= 1) v += __shfl_xor(v, off);
  return v;
}

// -------------------------------------------------------------------------
// invn + normalize + cast: zb[row][k] = bf16( z[row][k] / max(||z_row||,eps) )
__global__ __launch_bounds__(256) void k_normcast(const float* __restrict__ zi,
                                                  const float* __restrict__ zj,
                                                  ushort* __restrict__ zb, int N) {
  __shared__ float scratch[4];
  __shared__ float s_inv;
  int row = blockIdx.x;
  const float* src = (row < N) ? (zi + (size_t)row * D) : (zj + (size_t)(row - N) * D);
  float ss = 0.f;
  for (int k = threadIdx.x; k < D; k += 256) {
    float v = src[k];
    ss = fmaf(v, v, ss);
  }
  ss = wave_reduce_sum(ss);
  int lane = threadIdx.x & 63, wv = threadIdx.x >> 6;
  if (lane == 0) scratch[wv] = ss;
  __syncthreads();
  if (threadIdx.x == 0) {
    float t = scratch[0] + scratch[1] + scratch[2] + scratch[3];
    s_inv = 1.0f / fmaxf(sqrtf(t), 1e-12f);
  }
  __syncthreads();
  float sc = s_inv;
  ushort* dst = zb + (size_t)row * D;
  for (int k = threadIdx.x; k < D; k += 256) {
    __hip_bfloat16 h = __float2bfloat16(src[k] * sc);
    dst[k] = *reinterpret_cast<ushort*>(&h);
  }
}

// -------------------------------------------------------------------------
// sinv[j] = 1 / (2*shalf[j] - 1), shalf[j] = sum_i same(i,j)*rbf(i,j)
__global__ __launch_bounds__(256) void k_colsum(const int* __restrict__ labels,
                                                const float* __restrict__ zpos,
                                                float* __restrict__ sinv, int N) {
  __shared__ float scratch[4];
  int j = blockIdx.x;
  int lj = labels[j];
  float pj = zpos[j];
  float s = 0.f;
  for (int i = threadIdx.x; i < N; i += 256) {
    if (labels[i] == lj) {
      float d = zpos[i] - pj;
      s += __expf(-0.5f * d * d);
    }
  }
  s = wave_reduce_sum(s);
  int lane = threadIdx.x & 63, wv = threadIdx.x >> 6;
  if (lane == 0) scratch[wv] = s;
  __syncthreads();
  if (threadIdx.x == 0) {
    float t = scratch[0] + scratch[1] + scratch[2] + scratch[3];
    sinv[j] = 1.0f / (2.0f * t - 1.0f);
  }
}

// tt[i] = sum_j same(i,j)*rbf(i,j)*sinv[j]
__global__ __launch_bounds__(256) void k_tt(const int* __restrict__ labels,
                                            const float* __restrict__ zpos,
                                            const float* __restrict__ sinv,
                                            float* __restrict__ tt, int N) {
  __shared__ float scratch[4];
  int i = blockIdx.x;
  int li = labels[i];
  float pi = zpos[i];
  float s = 0.f;
  for (int j = threadIdx.x; j < N; j += 256) {
    if (labels[j] == li) {
      float d = zpos[j] - pi;
      s += __expf(-0.5f * d * d) * sinv[j];
    }
  }
  s = wave_reduce_sum(s);
  int lane = threadIdx.x & 63, wv = threadIdx.x >> 6;
  if (lane == 0) scratch[wv] = s;
  __syncthreads();
  if (threadIdx.x == 0) {
    tt[i] = scratch[0] + scratch[1] + scratch[2] + scratch[3];
  }
}

// -------------------------------------------------------------------------
// Main MFMA kernel. Each wave owns a 64x128 tile of the 4096x4096 sim matrix.
// 2048 wave-tiles = 64 row-tiles x 32 col-tiles; 4 waves/block -> 512 blocks.
// No LDS, no barriers: A and B fragments loaded directly from zb (4 MB,
// L2/LLC resident). Fixed softmax max = 10 (sim = 10*cos <= 10), so the
// per-row exp-sum and weighted-cross are plain sums -> 2D-decomposable.
// Writes s_ws[ct][row], c_ws[ct][row]; combined later.
__global__ __launch_bounds__(256, 2) void k_mfma(
    const ushort* __restrict__ zb, const int* __restrict__ labels,
    const float* __restrict__ zpos, const float* __restrict__ sinv,
    float* __restrict__ s_ws, float* __restrict__ c_ws, int N) {
  const int lane = threadIdx.x & 63;
  const int wv = threadIdx.x >> 6;
  const int gw = blockIdx.x * 4 + wv;
  const int rt = gw >> 5;                  // [0,64)
  const int ct = gw & 31;                  // [0,32)
  const int rowBase = rt * 64;
  const int colBase = ct * 128;
  const int colq = lane & 15;              // col within 16x16 frag / row within A frag
  const int laneg = lane >> 4;             // k-group
  const int twoN = 2 * N;

  f32x4 acc[4][8] = {};

  // ---- K loop: S_tile = A (64 x 512) * B^T (128 x 512), bf16 MFMA ----
#pragma unroll 2
  for (int ks = 0; ks < D; ks += 32) {
    const int koff = ks + laneg * 8;
    bf16x8 a[4], b[8];
#pragma unroll
    for (int rf = 0; rf < 4; ++rf)
      a[rf] = *reinterpret_cast<const bf16x8*>(
          zb + (size_t)(rowBase + rf * 16 + colq) * D + koff);
#pragma unroll
    for (int cf = 0; cf < 8; ++cf)
      b[cf] = *reinterpret_cast<const bf16x8*>(
          zb + (size_t)(colBase + cf * 16 + colq) * D + koff);
#pragma unroll
    for (int rf = 0; rf < 4; ++rf)
#pragma unroll
      for (int cf = 0; cf < 8; ++cf)
        acc[rf][cf] = __builtin_amdgcn_mfma_f32_16x16x32_bf16(a[rf], b[cf], acc[rf][cf], 0, 0, 0);
  }

  // ---- epilogue: per-row exp-sum (fixed max 10) + label/RBF-weighted cross ----
  // C layout: col = lane&15, row = (lane>>4)*4 + reg  [m89 verified]
  const int rmodBase = (rowBase >= N) ? rowBase - N : rowBase;
  const int cmodBase = (colBase >= N) ? colBase - N : colBase;
  float rpos[16];
  unsigned rlab = 0;
#pragma unroll
  for (int rf = 0; rf < 4; ++rf)
#pragma unroll
    for (int rg = 0; rg < 4; ++rg) {
      int idx = rf * 4 + rg;
      int r = rmodBase + rf * 16 + laneg * 4 + rg;
      rpos[idx] = zpos[r];
      rlab |= ((unsigned)labels[r] & 3u) << (idx * 2);
    }

  float s_p[16], c_p[16];
#pragma unroll
  for (int i = 0; i < 16; ++i) { s_p[i] = 0.f; c_p[i] = 0.f; }

#pragma unroll
  for (int cf = 0; cf < 8; ++cf) {
    int jc = cmodBase + cf * 16 + colq;
    int lc = labels[jc];
    float pc = zpos[jc];
    float si = sinv[jc];
    int col = colBase + cf * 16 + colq;
#pragma unroll
    for (int rf = 0; rf < 4; ++rf)
#pragma unroll
      for (int rg = 0; rg < 4; ++rg) {
        int idx = rf * 4 + rg;
        int row = rowBase + rf * 16 + laneg * 4 + rg;
        float sim = acc[rf][cf][rg] * INV_T;
        bool diag = (row == col);
        if (diag) sim = -INF_VAL;
        s_p[idx] += __expf(sim - 10.f);                 // exp(-1e8) == 0: diag drops out
        int lr = (int)((rlab >> (idx * 2)) & 3u);
        if (lr == lc && !diag) {
          float d = rpos[idx] - pc;
          c_p[idx] = fmaf(__expf(-0.5f * d * d) * si, sim, c_p[idx]);
        }
      }
  }

  // reduce each row across the 16 lanes that share it (xor within 16-lane group)
#pragma unroll
  for (int idx = 0; idx < 16; ++idx) {
#pragma unroll
    for (int off = 1; off < 16; off <<= 1) {
      s_p[idx] += __shfl_xor(s_p[idx], off);
      c_p[idx] += __shfl_xor(c_p[idx], off);
    }
  }
  if (colq == 0) {
#pragma unroll
    for (int rf = 0; rf < 4; ++rf)
#pragma unroll
      for (int rg = 0; rg < 4; ++rg) {
        int idx = rf * 4 + rg;
        int row = rowBase + rf * 16 + laneg * 4 + rg;
        s_ws[(size_t)ct * twoN + row] = s_p[idx];
        c_ws[(size_t)ct * twoN + row] = c_p[idx];
      }
  }
}

// -------------------------------------------------------------------------
// partial[a] = cross_a - wsum_a * (10 + log(sum_ct s_ws))
__global__ __launch_bounds__(256) void k_combine(const float* __restrict__ s_ws,
                                                 const float* __restrict__ c_ws,
                                                 const float* __restrict__ sinv,
                                                 const float* __restrict__ tt,
                                                 float* __restrict__ partial, int N) {
  int a = blockIdx.x * 256 + threadIdx.x;
  int twoN = 2 * N;
  if (a >= twoN) return;
  float s = 0.f, c = 0.f;
  for (int ctk = 0; ctk < NCT; ++ctk) {
    s += s_ws[(size_t)ctk * twoN + a];
    c += c_ws[(size_t)ctk * twoN + a];
  }
  int ir = (a >= N) ? a - N : a;
  float lse = 10.f + logf(s);
  float wsum = 2.f * tt[ir] - sinv[ir];
  partial[a] = c - wsum * lse;
}

// loss = (-1/N) * sum_a partial[a]
__global__ __launch_bounds__(256) void k_final(const float* __restrict__ partial,
                                               float* __restrict__ out, int N) {
  __shared__ float scratch[4];
  float s = 0.f;
  for (int a = threadIdx.x; a < 2 * N; a += 256) s += partial[a];
  s = wave_reduce_sum(s);
  int lane = threadIdx.x & 63, wv = threadIdx.x >> 6;
  if (lane == 0) scratch[wv] = s;
  __syncthreads();
  if (threadIdx.x == 0) {
    float t = scratch[0] + scratch[1] + scratch[2] + scratch[3];
    out[0] = (-1.0f / (float)N) * t;
  }
}

extern "C" void kernel_launch(void* const* d_in, const int* in_sizes, int n_in,
                              void* d_out, int out_size, void* d_ws, size_t ws_size,
                              hipStream_t stream) {
  (void)n_in; (void)out_size; (void)ws_size;
  const float* zi = (const float*)d_in[0];
  const float* zj = (const float*)d_in[1];
  const int* labels = (const int*)d_in[2];
  const float* zpos = (const float*)d_in[3];
  float* out = (float*)d_out;

  const int N = in_sizes[2];       // 2048
  const int twoN = 2 * N;

  // workspace layout: zb (bf16, 2N*D) | sinv | tt | s_ws | c_ws | partial
  char* wsb = (char*)d_ws;
  ushort* zb = (ushort*)wsb;                              // 4 MB
  float* sinv = (float*)(wsb + (size_t)twoN * D * 2);     // 8 KB
  float* tt = sinv + N;                                   // 8 KB
  float* s_ws = tt + N;                                   // NCT*2N floats
  float* c_ws = s_ws + (size_t)NCT * twoN;
  float* partial = c_ws + (size_t)NCT * twoN;

  k_normcast<<<twoN, 256, 0, stream>>>(zi, zj, zb, N);
  k_colsum<<<N, 256, 0, stream>>>(labels, zpos, sinv, N);
  k_tt<<<N, 256, 0, stream>>>(labels, zpos, sinv, tt, N);
  k_mfma<<<(twoN / 64) * NCT / 4, 256, 0, stream>>>(zb, labels, zpos, sinv, s_ws, c_ws, N);
  k_combine<<<(twoN + 255) / 256, 256, 0, stream>>>(s_ws, c_ws, sinv, tt, partial, N);
  k_final<<<1, 256, 0, stream>>>(partial, out, N);
}

// Round 5
// 70.389 us; speedup vs baseline: 5.4767x; 1.2282x over previous
//
#include <hip/hip_runtime.h>
#include <hip/hip_bf16.h>

// Problem constants (reference: N=2048, D=512, T=0.1, sigma=1, 4 classes)
#define D 512
#define INV_T 10.0f
#define INF_VAL 1e8f

#define BM 128
#define BN 128
#define BK 64
#define KSTEPS (D / BK)   // 8
#define NCHUNK 64         // 4096 / 64 column chunks for partials

typedef short bf16x8 __attribute__((ext_vector_type(8)));
typedef float f32x4 __attribute__((ext_vector_type(4)));

typedef __attribute__((address_space(3))) unsigned int lds_uint;
typedef __attribute__((address_space(1))) unsigned int gbl_uint;

__device__ __forceinline__ void async_copy16(const ushort* gsrc, ushort* ldst) {
  // 64 lanes x 16B -> 1 KB; LDS dest = wave-uniform base + lane*16 (linear)
  __builtin_amdgcn_global_load_lds((const gbl_uint*)gsrc, (lds_uint*)ldst, 16, 0, 0);
}

__device__ inline float wave_reduce_sum(float v) {
#pragma unroll
  for (int off = 32; off > 0; off >>= 1) v += __shfl_xor(v, off);
  return v;
}

// -------------------------------------------------------------------------
// invn + normalize + cast: zb[row][k] = bf16( z[row][k] / max(||z_row||,eps) )
__global__ __launch_bounds__(256) void k_normcast(const float* __restrict__ zi,
                                                  const float* __restrict__ zj,
                                                  ushort* __restrict__ zb, int N) {
  __shared__ float scratch[4];
  __shared__ float s_inv;
  int row = blockIdx.x;
  const float* src = (row < N) ? (zi + (size_t)row * D) : (zj + (size_t)(row - N) * D);
  float ss = 0.f;
  for (int k = threadIdx.x; k < D; k += 256) {
    float v = src[k];
    ss = fmaf(v, v, ss);
  }
  ss = wave_reduce_sum(ss);
  int lane = threadIdx.x & 63, wv = threadIdx.x >> 6;
  if (lane == 0) scratch[wv] = ss;
  __syncthreads();
  if (threadIdx.x == 0) {
    float t = scratch[0] + scratch[1] + scratch[2] + scratch[3];
    s_inv = 1.0f / fmaxf(sqrtf(t), 1e-12f);
  }
  __syncthreads();
  float sc = s_inv;
  ushort* dst = zb + (size_t)row * D;
  for (int k = threadIdx.x; k < D; k += 256) {
    __hip_bfloat16 h = __float2bfloat16(src[k] * sc);
    dst[k] = *reinterpret_cast<ushort*>(&h);
  }
}

// -------------------------------------------------------------------------
// sinv[j] = 1 / (2*shalf[j] - 1), shalf[j] = sum_i same(i,j)*rbf(i,j)
__global__ __launch_bounds__(256) void k_colsum(const int* __restrict__ labels,
                                                const float* __restrict__ zpos,
                                                float* __restrict__ sinv, int N) {
  __shared__ float scratch[4];
  int j = blockIdx.x;
  int lj = labels[j];
  float pj = zpos[j];
  float s = 0.f;
  for (int i = threadIdx.x; i < N; i += 256) {
    if (labels[i] == lj) {
      float d = zpos[i] - pj;
      s += __expf(-0.5f * d * d);
    }
  }
  s = wave_reduce_sum(s);
  int lane = threadIdx.x & 63, wv = threadIdx.x >> 6;
  if (lane == 0) scratch[wv] = s;
  __syncthreads();
  if (threadIdx.x == 0) {
    float t = scratch[0] + scratch[1] + scratch[2] + scratch[3];
    sinv[j] = 1.0f / (2.0f * t - 1.0f);
  }
}

// tt[i] = sum_j same(i,j)*rbf(i,j)*sinv[j]
__global__ __launch_bounds__(256) void k_tt(const int* __restrict__ labels,
                                            const float* __restrict__ zpos,
                                            const float* __restrict__ sinv,
                                            float* __restrict__ tt, int N) {
  __shared__ float scratch[4];
  int i = blockIdx.x;
  int li = labels[i];
  float pi = zpos[i];
  float s = 0.f;
  for (int j = threadIdx.x; j < N; j += 256) {
    if (labels[j] == li) {
      float d = zpos[j] - pi;
      s += __expf(-0.5f * d * d) * sinv[j];
    }
  }
  s = wave_reduce_sum(s);
  int lane = threadIdx.x & 63, wv = threadIdx.x >> 6;
  if (lane == 0) scratch[wv] = s;
  __syncthreads();
  if (threadIdx.x == 0) {
    tt[i] = scratch[0] + scratch[1] + scratch[2] + scratch[3];
  }
}

// -------------------------------------------------------------------------
// Main GEMM+epilogue. m97-style structure: 128x128 block tile, BK=64,
// global_load_lds staging (linear LDS dest, pre-swizzled global source,
// XOR-swizzled ds_read), 2-barrier K-loop. 4 waves, each owns a 64x64
// quadrant (4x4 frags of 16x16x32 bf16 MFMA). Fused epilogue: fixed-max
// softmax (sim = 10*cos <= 10) exp-sum + label/RBF-weighted cross.
// Writes s_ws/c_ws[chunk][row], chunk = 64-wide column chunk.
__global__ __launch_bounds__(256, 4) void k_gemm(
    const ushort* __restrict__ zb, const int* __restrict__ labels,
    const float* __restrict__ zpos, const float* __restrict__ sinv,
    float* __restrict__ s_ws, float* __restrict__ c_ws, int N) {
  __shared__ __align__(16) ushort As[BM * BK];   // 16 KB, row stride 128B (8 slots)
  __shared__ __align__(16) ushort Bs[BN * BK];   // 16 KB

  const int tid = threadIdx.x;
  const int lane = tid & 63;
  const int wv = tid >> 6;        // 0..3
  const int wr = wv >> 1;         // wave row quadrant
  const int wc = wv & 1;          // wave col quadrant
  const int colq = lane & 15;     // frag col / A-frag row
  const int laneg = lane >> 4;    // k-group

  // XCD-aware swizzle (1024 blocks, 8 XCDs, bijective since 1024 % 8 == 0)
  const int bid = blockIdx.x;
  const int L = (bid & 7) * 128 + (bid >> 3);
  const int rt = L >> 5;          // 0..31
  const int ct = L & 31;          // 0..31
  const int rowBase = rt * BM;
  const int colBase = ct * BN;
  const int twoN = 2 * N;

  // staging geometry: 1 inst = 8 rows x 128B; lane -> row lane>>3, slot lane&7.
  // LDS is linear; SOURCE is pre-swizzled so that read-side XOR finds it:
  // physical slot sp holds logical slot sp ^ (row&7); row&7 == lane>>3 here.
  const int srow = lane >> 3;
  const int sslot = (lane & 7) ^ srow;

  f32x4 acc[4][4] = {};

  for (int kt = 0; kt < KSTEPS; ++kt) {
    // ---- stage A & B tiles (each wave: rows [wv*32, wv*32+32) of both) ----
#pragma unroll
    for (int q = 0; q < 4; ++q) {
      int rloc = wv * 32 + q * 8;
      async_copy16(zb + (size_t)(rowBase + rloc + srow) * D + kt * BK + sslot * 8,
                   (ushort*)As + rloc * BK);
      async_copy16(zb + (size_t)(colBase + rloc + srow) * D + kt * BK + sslot * 8,
                   (ushort*)Bs + rloc * BK);
    }
    __syncthreads();   // drains vmcnt: tiles resident

    // ---- compute: 2 k-substeps of 32 ----
#pragma unroll
    for (int kk = 0; kk < 2; ++kk) {
      bf16x8 a[4], b[4];
      const int slot = (kk * 4 + laneg);
#pragma unroll
      for (int rf = 0; rf < 4; ++rf) {
        int r = wr * 64 + rf * 16 + colq;
        a[rf] = *reinterpret_cast<const bf16x8*>(
            reinterpret_cast<const char*>(As) + r * 128 + (slot ^ (r & 7)) * 16);
      }
#pragma unroll
      for (int cf = 0; cf < 4; ++cf) {
        int c = wc * 64 + cf * 16 + colq;
        b[cf] = *reinterpret_cast<const bf16x8*>(
            reinterpret_cast<const char*>(Bs) + c * 128 + (slot ^ (c & 7)) * 16);
      }
#pragma unroll
      for (int rf = 0; rf < 4; ++rf)
#pragma unroll
        for (int cf = 0; cf < 4; ++cf)
          acc[rf][cf] = __builtin_amdgcn_mfma_f32_16x16x32_bf16(a[rf], b[cf], acc[rf][cf], 0, 0, 0);
    }
    __syncthreads();   // LDS free for next K-tile
  }

  // ---- epilogue ----
  // C layout: col = lane&15, row = (lane>>4)*4 + reg  [m89 verified]
  const int wRowBase = rowBase + wr * 64;
  const int wColBase = colBase + wc * 64;
  const int rmodBase = (wRowBase >= N) ? wRowBase - N : wRowBase;
  const int cmodBase = (wColBase >= N) ? wColBase - N : wColBase;

  float rpos[16];
  unsigned rlab = 0;
#pragma unroll
  for (int rf = 0; rf < 4; ++rf)
#pragma unroll
    for (int rg = 0; rg < 4; ++rg) {
      int idx = rf * 4 + rg;
      int r = rmodBase + rf * 16 + laneg * 4 + rg;
      rpos[idx] = zpos[r];
      rlab |= ((unsigned)labels[r] & 3u) << (idx * 2);
    }

  float s_p[16], c_p[16];
#pragma unroll
  for (int i = 0; i < 16; ++i) { s_p[i] = 0.f; c_p[i] = 0.f; }

#pragma unroll
  for (int cf = 0; cf < 4; ++cf) {
    int jc = cmodBase + cf * 16 + colq;
    int lc = labels[jc];
    float pc = zpos[jc];
    float si = sinv[jc];
    int col = wColBase + cf * 16 + colq;
#pragma unroll
    for (int rf = 0; rf < 4; ++rf)
#pragma unroll
      for (int rg = 0; rg < 4; ++rg) {
        int idx = rf * 4 + rg;
        int row = wRowBase + rf * 16 + laneg * 4 + rg;
        float sim = acc[rf][cf][rg] * INV_T;
        bool diag = (row == col);
        if (diag) sim = -INF_VAL;
        s_p[idx] += __expf(sim - 10.f);        // exp(-1e8)==0: diag drops out
        int lr = (int)((rlab >> (idx * 2)) & 3u);
        if (lr == lc && !diag) {
          float d = rpos[idx] - pc;
          c_p[idx] = fmaf(__expf(-0.5f * d * d) * si, sim, c_p[idx]);
        }
      }
  }

  // reduce each row over the 16 lanes sharing it
#pragma unroll
  for (int idx = 0; idx < 16; ++idx) {
#pragma unroll
    for (int off = 1; off < 16; off <<= 1) {
      s_p[idx] += __shfl_xor(s_p[idx], off);
      c_p[idx] += __shfl_xor(c_p[idx], off);
    }
  }
  if (colq == 0) {
    int cc = ct * 2 + wc;      // 64-wide column chunk index
#pragma unroll
    for (int rf = 0; rf < 4; ++rf)
#pragma unroll
      for (int rg = 0; rg < 4; ++rg) {
        int idx = rf * 4 + rg;
        int row = wRowBase + rf * 16 + laneg * 4 + rg;
        s_ws[(size_t)cc * twoN + row] = s_p[idx];
        c_ws[(size_t)cc * twoN + row] = c_p[idx];
      }
  }
}

// -------------------------------------------------------------------------
// partial[a] = cross_a - wsum_a * (10 + log(sum_cc s_ws))
__global__ __launch_bounds__(256) void k_combine(const float* __restrict__ s_ws,
                                                 const float* __restrict__ c_ws,
                                                 const float* __restrict__ sinv,
                                                 const float* __restrict__ tt,
                                                 float* __restrict__ partial, int N) {
  int a = blockIdx.x * 256 + threadIdx.x;
  int twoN = 2 * N;
  if (a >= twoN) return;
  float s = 0.f, c = 0.f;
  for (int cc = 0; cc < NCHUNK; ++cc) {
    s += s_ws[(size_t)cc * twoN + a];
    c += c_ws[(size_t)cc * twoN + a];
  }
  int ir = (a >= N) ? a - N : a;
  float lse = 10.f + logf(s);
  float wsum = 2.f * tt[ir] - sinv[ir];
  partial[a] = c - wsum * lse;
}

// loss = (-1/N) * sum_a partial[a]
__global__ __launch_bounds__(256) void k_final(const float* __restrict__ partial,
                                               float* __restrict__ out, int N) {
  __shared__ float scratch[4];
  float s = 0.f;
  for (int a = threadIdx.x; a < 2 * N; a += 256) s += partial[a];
  s = wave_reduce_sum(s);
  int lane = threadIdx.x & 63, wv = threadIdx.x >> 6;
  if (lane == 0) scratch[wv] = s;
  __syncthreads();
  if (threadIdx.x == 0) {
    float t = scratch[0] + scratch[1] + scratch[2] + scratch[3];
    out[0] = (-1.0f / (float)N) * t;
  }
}

extern "C" void kernel_launch(void* const* d_in, const int* in_sizes, int n_in,
                              void* d_out, int out_size, void* d_ws, size_t ws_size,
                              hipStream_t stream) {
  (void)n_in; (void)out_size; (void)ws_size;
  const float* zi = (const float*)d_in[0];
  const float* zj = (const float*)d_in[1];
  const int* labels = (const int*)d_in[2];
  const float* zpos = (const float*)d_in[3];
  float* out = (float*)d_out;

  const int N = in_sizes[2];       // 2048
  const int twoN = 2 * N;

  // workspace layout: zb (bf16, 2N*D) | sinv | tt | s_ws | c_ws | partial
  char* wsb = (char*)d_ws;
  ushort* zb = (ushort*)wsb;                              // 4 MB
  float* sinv = (float*)(wsb + (size_t)twoN * D * 2);
  float* tt = sinv + N;
  float* s_ws = tt + N;                                   // NCHUNK*2N floats (1 MB)
  float* c_ws = s_ws + (size_t)NCHUNK * twoN;             // 1 MB
  float* partial = c_ws + (size_t)NCHUNK * twoN;

  k_normcast<<<twoN, 256, 0, stream>>>(zi, zj, zb, N);
  k_colsum<<<N, 256, 0, stream>>>(labels, zpos, sinv, N);
  k_tt<<<N, 256, 0, stream>>>(labels, zpos, sinv, tt, N);
  k_gemm<<<(twoN / BM) * (twoN / BN), 256, 0, stream>>>(zb, labels, zpos, sinv, s_ws, c_ws, N);
  k_combine<<<(twoN + 255) / 256, 256, 0, stream>>>(s_ws, c_ws, sinv, tt, partial, N);
  k_final<<<1, 256, 0, stream>>>(partial, out, N);
}

// Round 6
// 56.718 us; speedup vs baseline: 6.7967x; 1.2410x over previous
//
#include <hip/hip_runtime.h>
#include <hip/hip_bf16.h>

// Problem constants (reference: N=2048, D=512, T=0.1, sigma=1, 4 classes)
#define D 512
#define INV_T 10.0f
#define INF_VAL 1e8f

#define BM 128
#define BN 128
#define BK 64
#define KSTEPS (D / BK)   // 8
#define NTB 32            // 4096 / 128 tiles per dim
#define NBLK (NTB * (NTB + 1) / 2)   // 528 upper-triangle tiles
#define NCHUNK 64         // 4096 / 64 column chunks for partials

typedef short bf16x8 __attribute__((ext_vector_type(8)));
typedef float f32x4 __attribute__((ext_vector_type(4)));

typedef __attribute__((address_space(3))) unsigned int lds_uint;
typedef __attribute__((address_space(1))) unsigned int gbl_uint;

__device__ __forceinline__ void async_copy16(const ushort* gsrc, ushort* ldst) {
  // 64 lanes x 16B -> 1 KB; LDS dest = wave-uniform base + lane*16 (linear)
  __builtin_amdgcn_global_load_lds((const gbl_uint*)gsrc, (lds_uint*)ldst, 16, 0, 0);
}

__device__ inline float wave_reduce_sum(float v) {
#pragma unroll
  for (int off = 32; off > 0; off >>= 1) v += __shfl_xor(v, off);
  return v;
}

__device__ __forceinline__ ushort f2bf(float x) {
  __hip_bfloat16 h = __float2bfloat16(x);
  return *reinterpret_cast<ushort*>(&h);
}

// -------------------------------------------------------------------------
// Fused prep: blocks [0,1024) normalize+cast (wave-per-row, 4 rows/block);
// blocks [1024, 3072) compute sinv[j] = 1/(2*shalf[j]-1).
__global__ __launch_bounds__(256) void k_prep(const float* __restrict__ zi,
                                              const float* __restrict__ zj,
                                              ushort* __restrict__ zb,
                                              const int* __restrict__ labels,
                                              const float* __restrict__ zpos,
                                              float* __restrict__ sinv, int N) {
  int b = blockIdx.x;
  if (b < 1024) {
    // --- normcast: one row per wave ---
    int wv = threadIdx.x >> 6, lane = threadIdx.x & 63;
    int row = b * 4 + wv;
    const float* src = (row < N) ? (zi + (size_t)row * D) : (zj + (size_t)(row - N) * D);
    const float4* s4 = reinterpret_cast<const float4*>(src);
    float4 v0 = s4[lane];
    float4 v1 = s4[lane + 64];
    float ss = 0.f;
    ss = fmaf(v0.x, v0.x, ss); ss = fmaf(v0.y, v0.y, ss);
    ss = fmaf(v0.z, v0.z, ss); ss = fmaf(v0.w, v0.w, ss);
    ss = fmaf(v1.x, v1.x, ss); ss = fmaf(v1.y, v1.y, ss);
    ss = fmaf(v1.z, v1.z, ss); ss = fmaf(v1.w, v1.w, ss);
    ss = wave_reduce_sum(ss);
    float sc = 1.0f / fmaxf(sqrtf(ss), 1e-12f);
    ushort4 o0 = {f2bf(v0.x * sc), f2bf(v0.y * sc), f2bf(v0.z * sc), f2bf(v0.w * sc)};
    ushort4 o1 = {f2bf(v1.x * sc), f2bf(v1.y * sc), f2bf(v1.z * sc), f2bf(v1.w * sc)};
    ushort4* dst = reinterpret_cast<ushort4*>(zb + (size_t)row * D);
    dst[lane] = o0;
    dst[lane + 64] = o1;
  } else {
    // --- colsum: one j per block (proven round-4 body) ---
    __shared__ float scratch[4];
    int j = b - 1024;
    int lj = labels[j];
    float pj = zpos[j];
    float s = 0.f;
    for (int i = threadIdx.x; i < N; i += 256) {
      if (labels[i] == lj) {
        float d = zpos[i] - pj;
        s += __expf(-0.5f * d * d);
      }
    }
    s = wave_reduce_sum(s);
    int lane = threadIdx.x & 63, wv = threadIdx.x >> 6;
    if (lane == 0) scratch[wv] = s;
    __syncthreads();
    if (threadIdx.x == 0) {
      float t = scratch[0] + scratch[1] + scratch[2] + scratch[3];
      sinv[j] = 1.0f / (2.0f * t - 1.0f);
    }
  }
}

// tt[i] = sum_j same(i,j)*rbf(i,j)*sinv[j]
__global__ __launch_bounds__(256) void k_tt(const int* __restrict__ labels,
                                            const float* __restrict__ zpos,
                                            const float* __restrict__ sinv,
                                            float* __restrict__ tt, int N) {
  __shared__ float scratch[4];
  int i = blockIdx.x;
  int li = labels[i];
  float pi = zpos[i];
  float s = 0.f;
  for (int j = threadIdx.x; j < N; j += 256) {
    if (labels[j] == li) {
      float d = zpos[j] - pi;
      s += __expf(-0.5f * d * d) * sinv[j];
    }
  }
  s = wave_reduce_sum(s);
  int lane = threadIdx.x & 63, wv = threadIdx.x >> 6;
  if (lane == 0) scratch[wv] = s;
  __syncthreads();
  if (threadIdx.x == 0) {
    tt[i] = scratch[0] + scratch[1] + scratch[2] + scratch[3];
  }
}

// -------------------------------------------------------------------------
// Symmetric GEMM + dual epilogue. Upper-triangle 128x128 tiles only (528
// blocks). Double-buffered LDS, prefetch-next-before-compute, one barrier
// per K-step (minimum 2-phase, catalog T3). Each off-diagonal tile emits
// BOTH row partials (forward) and column partials (transpose: sim, exp,
// rbf, label-mask all symmetric; cross swaps the sinv index). Diagonal
// tiles stage A only (B == A) and emit forward partials only.
// Coverage of s_ws/c_ws[chunk][row]: forward fills rtile<=ctile cells,
// transpose fills rtile>ctile — each cell written exactly once.
__global__ __launch_bounds__(256, 2) void k_gemm(
    const ushort* __restrict__ zb, const int* __restrict__ labels,
    const float* __restrict__ zpos, const float* __restrict__ sinv,
    float* __restrict__ s_ws, float* __restrict__ c_ws, int N) {
  __shared__ __align__(16) ushort sT[2][2][BM * BK];   // [buf][A/B], 64 KB

  const int tid = threadIdx.x;
  const int lane = tid & 63;
  const int wv = tid >> 6;        // 0..3
  const int wr = wv >> 1;         // wave row quadrant
  const int wc = wv & 1;          // wave col quadrant
  const int colq = lane & 15;
  const int laneg = lane >> 4;
  const int twoN = 2 * N;

  // XCD swizzle (528 % 8 == 0 -> simple form bijective), then triangle unrank
  const int bid = blockIdx.x;
  int L = (bid & 7) * (NBLK / 8) + (bid >> 3);
  int u = L, rt = 0;
  while (u >= NTB - rt) { u -= NTB - rt; ++rt; }
  const int ct = rt + u;                 // rt <= ct
  const bool diag = (rt == ct);
  const int rowBase = rt * BM;
  const int colBase = ct * BN;

  // staging geometry (identical to proven round-4 kernel)
  const int srow = lane >> 3;
  const int sslot = (lane & 7) ^ srow;

  f32x4 acc[4][4] = {};

  // ---- prologue: stage K-tile 0 into buffer 0 ----
  {
#pragma unroll
    for (int q = 0; q < 4; ++q) {
      int rloc = wv * 32 + q * 8;
      async_copy16(zb + (size_t)(rowBase + rloc + srow) * D + 0 * BK + sslot * 8,
                   (ushort*)sT[0][0] + rloc * BK);
      if (!diag)
        async_copy16(zb + (size_t)(colBase + rloc + srow) * D + 0 * BK + sslot * 8,
                     (ushort*)sT[0][1] + rloc * BK);
    }
  }
  __syncthreads();

  int cur = 0;
#pragma unroll
  for (int kt = 0; kt < KSTEPS; ++kt) {
    // ---- prefetch next K-tile into the other buffer (overlaps compute) ----
    if (kt + 1 < KSTEPS) {
#pragma unroll
      for (int q = 0; q < 4; ++q) {
        int rloc = wv * 32 + q * 8;
        async_copy16(zb + (size_t)(rowBase + rloc + srow) * D + (kt + 1) * BK + sslot * 8,
                     (ushort*)sT[cur ^ 1][0] + rloc * BK);
        if (!diag)
          async_copy16(zb + (size_t)(colBase + rloc + srow) * D + (kt + 1) * BK + sslot * 8,
                       (ushort*)sT[cur ^ 1][1] + rloc * BK);
      }
    }

    // ---- compute current buffer ----
    const char* Ab = reinterpret_cast<const char*>(sT[cur][0]);
    const char* Bb = diag ? Ab : reinterpret_cast<const char*>(sT[cur][1]);
#pragma unroll
    for (int kk = 0; kk < 2; ++kk) {
      bf16x8 a[4], b[4];
      const int slot = kk * 4 + laneg;
#pragma unroll
      for (int rf = 0; rf < 4; ++rf) {
        int r = wr * 64 + rf * 16 + colq;
        a[rf] = *reinterpret_cast<const bf16x8*>(Ab + r * 128 + (slot ^ (r & 7)) * 16);
      }
#pragma unroll
      for (int cf = 0; cf < 4; ++cf) {
        int c = wc * 64 + cf * 16 + colq;
        b[cf] = *reinterpret_cast<const bf16x8*>(Bb + c * 128 + (slot ^ (c & 7)) * 16);
      }
#pragma unroll
      for (int rf = 0; rf < 4; ++rf)
#pragma unroll
        for (int cf = 0; cf < 4; ++cf)
          acc[rf][cf] = __builtin_amdgcn_mfma_f32_16x16x32_bf16(a[rf], b[cf], acc[rf][cf], 0, 0, 0);
    }

    if (kt + 1 < KSTEPS) {
      __syncthreads();   // drains vmcnt (prefetch landed) + all reads done
      cur ^= 1;
    }
  }

  // ---- dual epilogue ----
  // C layout: col = lane&15, row = (lane>>4)*4 + reg  [m89 verified]
  const int wRowBase = rowBase + wr * 64;
  const int wColBase = colBase + wc * 64;
  const int rmodBase = (wRowBase >= N) ? wRowBase - N : wRowBase;
  const int cmodBase = (wColBase >= N) ? wColBase - N : wColBase;

  float rpos[16], rsinv[16];
  unsigned rlab = 0;
#pragma unroll
  for (int rf = 0; rf < 4; ++rf)
#pragma unroll
    for (int rg = 0; rg < 4; ++rg) {
      int idx = rf * 4 + rg;
      int r = rmodBase + rf * 16 + laneg * 4 + rg;
      rpos[idx] = zpos[r];
      rsinv[idx] = sinv[r];
      rlab |= ((unsigned)labels[r] & 3u) << (idx * 2);
    }

  float s_p[16], c_p[16], sc_p[4], cc_p[4];
#pragma unroll
  for (int i = 0; i < 16; ++i) { s_p[i] = 0.f; c_p[i] = 0.f; }

#pragma unroll
  for (int cf = 0; cf < 4; ++cf) {
    int jc = cmodBase + cf * 16 + colq;
    int lc = labels[jc];
    float pc = zpos[jc];
    float si = sinv[jc];
    int col = wColBase + cf * 16 + colq;
    float scf = 0.f, ccf = 0.f;
#pragma unroll
    for (int rf = 0; rf < 4; ++rf)
#pragma unroll
      for (int rg = 0; rg < 4; ++rg) {
        int idx = rf * 4 + rg;
        int row = wRowBase + rf * 16 + laneg * 4 + rg;
        float sim = acc[rf][cf][rg] * INV_T;
        bool dg = (row == col);
        if (dg) sim = -INF_VAL;
        float e = __expf(sim - 10.f);          // exp(-1e8)==0: diag drops out
        s_p[idx] += e;                          // forward row-sum
        scf += e;                               // transpose col-sum (same e)
        int lr = (int)((rlab >> (idx * 2)) & 3u);
        if (lr == lc && !dg) {
          float d = rpos[idx] - pc;
          float w = __expf(-0.5f * d * d);
          c_p[idx] = fmaf(w * si, sim, c_p[idx]);          // fw[r,c] = w*sinv[c]
          ccf = fmaf(w * rsinv[idx], sim, ccf);            // fw[c,r] = w*sinv[r]
        }
      }
    sc_p[cf] = scf;
    cc_p[cf] = ccf;
  }

  // forward: reduce each row over the 16 lanes sharing it
#pragma unroll
  for (int idx = 0; idx < 16; ++idx) {
#pragma unroll
    for (int off = 1; off < 16; off <<= 1) {
      s_p[idx] += __shfl_xor(s_p[idx], off);
      c_p[idx] += __shfl_xor(c_p[idx], off);
    }
  }
  if (colq == 0) {
    int cc = ct * 2 + wc;
#pragma unroll
    for (int rf = 0; rf < 4; ++rf)
#pragma unroll
      for (int rg = 0; rg < 4; ++rg) {
        int idx = rf * 4 + rg;
        int row = wRowBase + rf * 16 + laneg * 4 + rg;
        s_ws[(size_t)cc * twoN + row] = s_p[idx];
        c_ws[(size_t)cc * twoN + row] = c_p[idx];
      }
  }

  // transpose: reduce each column over laneg groups (lanes colq, +16, +32, +48)
  if (!diag) {
#pragma unroll
    for (int cf = 0; cf < 4; ++cf) {
      sc_p[cf] += __shfl_xor(sc_p[cf], 16);
      sc_p[cf] += __shfl_xor(sc_p[cf], 32);
      cc_p[cf] += __shfl_xor(cc_p[cf], 16);
      cc_p[cf] += __shfl_xor(cc_p[cf], 32);
    }
    if (laneg == 0) {
      int cct = rt * 2 + wr;
#pragma unroll
      for (int cf = 0; cf < 4; ++cf) {
        int rowt = wColBase + cf * 16 + colq;
        s_ws[(size_t)cct * twoN + rowt] = sc_p[cf];
        c_ws[(size_t)cct * twoN + rowt] = cc_p[cf];
      }
    }
  }
}

// -------------------------------------------------------------------------
// partial[a] = cross_a - wsum_a * (10 + log(sum_cc s_ws))
__global__ __launch_bounds__(256) void k_combine(const float* __restrict__ s_ws,
                                                 const float* __restrict__ c_ws,
                                                 const float* __restrict__ sinv,
                                                 const float* __restrict__ tt,
                                                 float* __restrict__ partial, int N) {
  int a = blockIdx.x * 256 + threadIdx.x;
  int twoN = 2 * N;
  if (a >= twoN) return;
  float s = 0.f, c = 0.f;
  for (int cc = 0; cc < NCHUNK; ++cc) {
    s += s_ws[(size_t)cc * twoN + a];
    c += c_ws[(size_t)cc * twoN + a];
  }
  int ir = (a >= N) ? a - N : a;
  float lse = 10.f + logf(s);
  float wsum = 2.f * tt[ir] - sinv[ir];
  partial[a] = c - wsum * lse;
}

// loss = (-1/N) * sum_a partial[a]
__global__ __launch_bounds__(256) void k_final(const float* __restrict__ partial,
                                               float* __restrict__ out, int N) {
  __shared__ float scratch[4];
  float s = 0.f;
  for (int a = threadIdx.x; a < 2 * N; a += 256) s += partial[a];
  s = wave_reduce_sum(s);
  int lane = threadIdx.x & 63, wv = threadIdx.x >> 6;
  if (lane == 0) scratch[wv] = s;
  __syncthreads();
  if (threadIdx.x == 0) {
    float t = scratch[0] + scratch[1] + scratch[2] + scratch[3];
    out[0] = (-1.0f / (float)N) * t;
  }
}

extern "C" void kernel_launch(void* const* d_in, const int* in_sizes, int n_in,
                              void* d_out, int out_size, void* d_ws, size_t ws_size,
                              hipStream_t stream) {
  (void)n_in; (void)out_size; (void)ws_size;
  const float* zi = (const float*)d_in[0];
  const float* zj = (const float*)d_in[1];
  const int* labels = (const int*)d_in[2];
  const float* zpos = (const float*)d_in[3];
  float* out = (float*)d_out;

  const int N = in_sizes[2];       // 2048
  const int twoN = 2 * N;

  // workspace layout: zb (bf16, 2N*D) | sinv | tt | s_ws | c_ws | partial
  char* wsb = (char*)d_ws;
  ushort* zb = (ushort*)wsb;                              // 4 MB
  float* sinv = (float*)(wsb + (size_t)twoN * D * 2);
  float* tt = sinv + N;
  float* s_ws = tt + N;                                   // 1 MB
  float* c_ws = s_ws + (size_t)NCHUNK * twoN;             // 1 MB
  float* partial = c_ws + (size_t)NCHUNK * twoN;

  k_prep<<<1024 + 2048, 256, 0, stream>>>(zi, zj, zb, labels, zpos, sinv, N);
  k_tt<<<N, 256, 0, stream>>>(labels, zpos, sinv, tt, N);
  k_gemm<<<NBLK, 256, 0, stream>>>(zb, labels, zpos, sinv, s_ws, c_ws, N);
  k_combine<<<(twoN + 255) / 256, 256, 0, stream>>>(s_ws, c_ws, sinv, tt, partial, N);
  k_final<<<1, 256, 0, stream>>>(partial, out, N);
}